// Round 10
// baseline (296.733 us; speedup 1.0000x reference)
//
#include <hip/hip_runtime.h>
#include <cstdint>
#include <cstddef>

#define H_DIM 768
#define NHEADS 12
#define HSZ 64
#define PATCH 512
#define MTOT 16384                 // 8*4*512 tokens
#define SZT ((long)MTOT * H_DIM)   // elements per [16384,768] matrix

using short8 = __attribute__((ext_vector_type(8))) short;   // 8 bf16 (4 VGPRs)
using f32x4  = __attribute__((ext_vector_type(4))) float;   // MFMA accumulator
using us4    = __attribute__((ext_vector_type(4))) unsigned short;

// async global->LDS, 16B per lane; LDS dest = wave-uniform base + lane*16
#define GLL16(gp, lp) __builtin_amdgcn_global_load_lds( \
    (const __attribute__((address_space(1))) void*)(gp), \
    (__attribute__((address_space(3))) void*)(lp), 16, 0, 0)

#define SB0() __builtin_amdgcn_sched_barrier(0)

__device__ __forceinline__ unsigned short bf16rne(float x) {
    unsigned v = __float_as_uint(x);
    v += 0x7fff + ((v >> 16) & 1);
    return (unsigned short)(v >> 16);
}

// ------------------------------------------------------------------
// prep_all: fused preprocessing in ONE launch.
// blocks [0,6144): X fp32 -> X~ bf16 RNE (8 elems/thread).
// blocks [6144,6720): 4 x 144 weight-transpose tiles (Wq,Wk,Wv,Wo -> bf16 RNE).
// ------------------------------------------------------------------
__global__ __launch_bounds__(256) void prep_all(
    const float* __restrict__ X, unsigned short* __restrict__ Xb,
    const float* __restrict__ Wq, const float* __restrict__ Wk,
    const float* __restrict__ Wv, const float* __restrict__ Wo,
    unsigned short* __restrict__ WqH, unsigned short* __restrict__ WkH,
    unsigned short* __restrict__ WvH, unsigned short* __restrict__ WoH)
{
    __shared__ float T[64][65];
    const int b = blockIdx.x;
    const int tid = threadIdx.x;

    if (b < 6144) {
        const long i = ((long)b * 256 + tid) * 8;
        float4 a = *(const float4*)&X[i];
        float4 c = *(const float4*)&X[i + 4];
        float xs[8] = {a.x, a.y, a.z, a.w, c.x, c.y, c.z, c.w};
        us4 h0, h1;
        #pragma unroll
        for (int j = 0; j < 4; ++j) { h0[j] = bf16rne(xs[j]); h1[j] = bf16rne(xs[j + 4]); }
        *(us4*)&Xb[i] = h0; *(us4*)&Xb[i + 4] = h1;
        return;
    }

    const int w     = b - 6144;
    const int which = w / 144;                 // 0=Wq 1=Wk 2=Wv 3=Wo
    const int t     = w % 144;
    const int kt    = (t / 12) * 64, nt = (t % 12) * 64;
    const float* W  = (which == 0) ? Wq : (which == 1) ? Wk : (which == 2) ? Wv : Wo;
    unsigned short* Whi = (which == 0) ? WqH : (which == 1) ? WkH : (which == 2) ? WvH : WoH;

    const int r = tid >> 2, c16 = (tid & 3) * 16;
    #pragma unroll
    for (int j = 0; j < 4; ++j) {
        float4 v = *(const float4*)&W[(long)(kt + r) * H_DIM + nt + c16 + j * 4];
        T[r][c16 + j*4 + 0] = v.x; T[r][c16 + j*4 + 1] = v.y;
        T[r][c16 + j*4 + 2] = v.z; T[r][c16 + j*4 + 3] = v.w;
    }
    __syncthreads();
    unsigned short* ph = &Whi[(long)(nt + r) * H_DIM + kt + c16];
    #pragma unroll
    for (int j = 0; j < 16; ++j)
        ph[j] = bf16rne(T[c16 + j][r]);
}

// ------------------------------------------------------------------
// qkv_gemm v4 (frozen from R6/R7, best timed total): block 256x128, 4 waves
// as 2M x 2N, per-wave 128x64 (acc[8][4]), BK=64, 48 KB LDS, grid 1152,
// XCD-bijective remap cpx=144. Vp stored LINEAR.
// rocprof replay durs distorted for this kernel (R6 lesson) — timed total only.
// ------------------------------------------------------------------
__global__ __launch_bounds__(256, 2) void qkv_gemm(
    const unsigned short* __restrict__ Xb,
    const unsigned short* __restrict__ WqH, const unsigned short* __restrict__ WkH,
    const unsigned short* __restrict__ WvH,
    const float* __restrict__ bq, const float* __restrict__ bk, const float* __restrict__ bv,
    float qscale,
    unsigned short* __restrict__ Qt, unsigned short* __restrict__ Kp,
    unsigned short* __restrict__ Vp)
{
    __shared__ unsigned short As[16384];     // 256 rows x 64 k (swizzled chunks)
    __shared__ unsigned short Bs[8192];      // 128 rows x 64 k

    const int s   = blockIdx.x;                     // 0..1151, hw dispatch order
    const int lid = (s & 7) * 144 + (s >> 3);       // bijective, 1152 = 8*144
    const int bx  = lid % 18;
    const int by  = lid / 18;                       // 0..63

    const int mat = bx / 6;
    const int n0  = (bx % 6) * 128;
    const int m0  = by * 256;
    const unsigned short* Bh = (mat == 0) ? WqH : (mat == 1) ? WkH : WvH;
    const float* bias        = (mat == 0) ? bq  : (mat == 1) ? bk  : bv;
    const float scale        = (mat == 0) ? qscale : 1.0f;

    const int tid  = threadIdx.x;
    const int lane = tid & 63;
    const int wv   = tid >> 6;
    const int wr   = wv >> 1, wc = wv & 1;
    const int q    = lane >> 4, l15 = lane & 15;

    const int srow   = tid >> 3;                        // 0..31
    const int schunk = (tid & 7) ^ (srow & 7);          // swizzled global chunk

    char* ldsA = (char*)(&As[0]) + (wv << 10);
    char* ldsB = (char*)(&Bs[0]) + (wv << 10);

    f32x4 acc[8][4];
    #pragma unroll
    for (int i = 0; i < 8; ++i)
        #pragma unroll
        for (int j = 0; j < 4; ++j) acc[i][j] = 0;

    const int swz = (l15 & 7);   // row-dependent chunk swizzle for fragment reads

    for (int k0 = 0; k0 < H_DIM; k0 += 64) {
        #pragma unroll
        for (int i = 0; i < 8; ++i)
            GLL16(Xb + (long)(m0 + i * 32 + srow) * H_DIM + k0 + schunk * 8,
                  ldsA + i * 4096);
        #pragma unroll
        for (int i = 0; i < 4; ++i)
            GLL16(Bh + (long)(n0 + i * 32 + srow) * H_DIM + k0 + schunk * 8,
                  ldsB + i * 4096);
        __syncthreads();

        #pragma unroll
        for (int ks = 0; ks < 2; ++ks) {
            const int pc = ((ks * 4 + q) ^ swz) * 8;
            short8 ah[8], bh[4];
            #pragma unroll
            for (int t = 0; t < 8; ++t) {
                const int mr = wr * 128 + t * 16 + l15;
                ah[t] = *(const short8*)&As[mr * 64 + pc];
            }
            #pragma unroll
            for (int t = 0; t < 4; ++t) {
                const int nr = wc * 64 + t * 16 + l15;
                bh[t] = *(const short8*)&Bs[nr * 64 + pc];
            }
            #pragma unroll
            for (int mt = 0; mt < 8; ++mt)
                #pragma unroll
                for (int nt = 0; nt < 4; ++nt)
                    acc[mt][nt] = __builtin_amdgcn_mfma_f32_16x16x32_bf16(ah[mt], bh[nt], acc[mt][nt], 0, 0, 0);
        }
        __syncthreads();
    }

    // epilogue: C/D layout col = lane&15, row = quad*4 + reg
    #pragma unroll
    for (int nt = 0; nt < 4; ++nt) {
        const int col = n0 + wc * 64 + nt * 16 + l15;
        const float bcol = bias[col];
        const int h = col >> 6, d = col & 63;
        #pragma unroll
        for (int mt = 0; mt < 8; ++mt) {
            const int rowB = m0 + wr * 128 + mt * 16 + q * 4;
            #pragma unroll
            for (int r = 0; r < 4; ++r) {
                const int row = rowB + r;
                const float val = (acc[mt][nt][r] + bcol) * scale;
                const int bm = row >> 9, p = row & 511;
                const int bmh = bm * NHEADS + h;
                if (mat == 0) {
                    const long idx = ((long)bmh * 8 + (p >> 6)) * 4096 + (long)(p & 63) * 64 + d;
                    Qt[idx] = bf16rne(val);
                } else if (mat == 1) {
                    Kp[(long)bmh * 32768 + (long)p * 64 + d] = bf16rne(val);
                } else {
                    Vp[(long)bmh * 32768 + (long)d * 512 + p] = bf16rne(val);
                }
            }
        }
    }
}

// ------------------------------------------------------------------
// attn2 (R9 A/B: the R3 SYNC-staged single-buffer version).
// Isolates the R4 confound: sync staging at 4 blocks/CU (TLP hides the
// stage latency) vs async dbuf at 3 blocks/CU. 35.4 KB LDS.
// Flash attention, no max-tracking, base-2 softmax, all bf16.
// ------------------------------------------------------------------
__global__ __launch_bounds__(256, 4) void attn2(
    const unsigned short* __restrict__ Qt,
    const unsigned short* __restrict__ Kp, const unsigned short* __restrict__ Vp,
    unsigned short* __restrict__ Ctx)
{
    __shared__ unsigned short Ks[4096];      // [key][swz-chunk*8] bf16
    __shared__ unsigned short Vs[4096];      // [d][swz-chunk*8] bf16
    __shared__ unsigned short Ps[128 * 72];  // P bf16, padded stride 72
    __shared__ float red[128][2];            // cross-wave row sum (finalize)

    const int tid  = threadIdx.x;
    const int lane = tid & 63;
    const int wv   = tid >> 6;
    const int wr   = wv >> 1, wc = wv & 1;
    const int q    = lane >> 4, l15 = lane & 15;

    const int s   = blockIdx.x + 4 * blockIdx.y;    // hw dispatch order
    const int lid = (s & 7) * 192 + (s >> 3);       // 1536 wgs, cpx = 192
    const int qt2 = lid & 3;     // 0..3
    const int bmh = lid >> 2;    // 0..383

    // ---- Q fragments (loop-invariant) ----
    short8 qh[4][2];
    const long qtile = ((long)bmh * 8 + qt2 * 2 + wr) * 4096;
    #pragma unroll
    for (int mt = 0; mt < 4; ++mt)
        #pragma unroll
        for (int ks = 0; ks < 2; ++ks)
            qh[mt][ks] = *(const short8*)&Qt[qtile + (mt * 16 + l15) * 64 + ks * 32 + q * 8];

    f32x4 ctx[4][2];
    float l_cur[4][4];
    #pragma unroll
    for (int mt = 0; mt < 4; ++mt) {
        ctx[mt][0] = 0; ctx[mt][1] = 0;
        #pragma unroll
        for (int r = 0; r < 4; ++r) l_cur[mt][r] = 0.0f;
    }

    const long khead = (long)bmh * 32768;
    const int srow   = tid >> 3;                               // 0..31
    const int gchunk = ((tid & 7) ^ (srow & 7)) * 8;           // swizzled source chunk
    char* dK = (char*)&Ks[0] + (wv << 10);
    char* dV = (char*)&Vs[0] + (wv << 10);

    for (int kt = 0; kt < 8; ++kt) {
        __syncthreads();   // prev iter's QK/PV reads of Ks/Vs/Ps complete
        {
            const long kb = khead + (long)kt * 64 * 64;
            GLL16(Kp + kb + (long)srow * 64 + gchunk,        dK);
            GLL16(Kp + kb + (long)(srow + 32) * 64 + gchunk, dK + 4096);
            const long vb = khead + (long)kt * 64;
            GLL16(Vp + vb + (long)srow * 512 + gchunk,        dV);
            GLL16(Vp + vb + (long)(srow + 32) * 512 + gchunk, dV + 4096);
        }
        __syncthreads();   // staging landed (barrier drains vmcnt)

        // ---- S = Q K^T (1-pass) : rows wr*64+, keys wc*32+ ----
        f32x4 sv[4][2];
        #pragma unroll
        for (int mt = 0; mt < 4; ++mt) { sv[mt][0] = 0; sv[mt][1] = 0; }
        short8 kf[2][2];
        #pragma unroll
        for (int nt = 0; nt < 2; ++nt)
            #pragma unroll
            for (int ks = 0; ks < 2; ++ks) {
                const int key = wc * 32 + nt * 16 + l15;
                const int phys = (q + ks * 4) ^ (key & 7);
                kf[nt][ks] = *(const short8*)&Ks[key * 64 + phys * 8];
            }
        #pragma unroll
        for (int mt = 0; mt < 4; ++mt)
            #pragma unroll
            for (int nt = 0; nt < 2; ++nt)
                #pragma unroll
                for (int ks = 0; ks < 2; ++ks)
                    sv[mt][nt] = __builtin_amdgcn_mfma_f32_16x16x32_bf16(qh[mt][ks], kf[nt][ks], sv[mt][nt], 0, 0, 0);

        // ---- p = exp2(s); accumulate l; write P bf16 ----
        #pragma unroll
        for (int mt = 0; mt < 4; ++mt)
            #pragma unroll
            for (int r = 0; r < 4; ++r) {
                const int row = wr * 64 + mt * 16 + q * 4 + r;
                const float p0 = __builtin_amdgcn_exp2f(sv[mt][0][r]);
                const float p1 = __builtin_amdgcn_exp2f(sv[mt][1][r]);
                l_cur[mt][r] += p0 + p1;
                Ps[row * 72 + wc * 32 + l15]      = bf16rne(p0);
                Ps[row * 72 + wc * 32 + 16 + l15] = bf16rne(p1);
            }
        __syncthreads();

        // ---- ctx += P V (1-pass) : rows wr*64+, d-cols wc*32+ ----
        short8 pf[4][2], vf[2][2];
        #pragma unroll
        for (int mt = 0; mt < 4; ++mt)
            #pragma unroll
            for (int ks = 0; ks < 2; ++ks)
                pf[mt][ks] = *(const short8*)&Ps[(wr * 64 + mt * 16 + l15) * 72 + ks * 32 + q * 8];
        #pragma unroll
        for (int nt = 0; nt < 2; ++nt)
            #pragma unroll
            for (int ks = 0; ks < 2; ++ks) {
                const int d = wc * 32 + nt * 16 + l15;
                const int phys = (q + ks * 4) ^ (d & 7);
                vf[nt][ks] = *(const short8*)&Vs[d * 64 + phys * 8];
            }
        #pragma unroll
        for (int mt = 0; mt < 4; ++mt)
            #pragma unroll
            for (int nt = 0; nt < 2; ++nt)
                #pragma unroll
                for (int ks = 0; ks < 2; ++ks)
                    ctx[mt][nt] = __builtin_amdgcn_mfma_f32_16x16x32_bf16(pf[mt][ks], vf[nt][ks], ctx[mt][nt], 0, 0, 0);
    }

    // ---- finalize l (in-quad + cross-wave sum), normalize, store ctx bf16 ----
    #pragma unroll
    for (int mt = 0; mt < 4; ++mt)
        #pragma unroll
        for (int r = 0; r < 4; ++r) {
            float v = l_cur[mt][r];
            v += __shfl_xor(v, 1);
            v += __shfl_xor(v, 2);
            v += __shfl_xor(v, 4);
            v += __shfl_xor(v, 8);
            if (l15 == 0) red[wr * 64 + mt * 16 + q * 4 + r][wc] = v;
        }
    __syncthreads();
    #pragma unroll
    for (int mt = 0; mt < 4; ++mt)
        #pragma unroll
        for (int r = 0; r < 4; ++r) {
            const int row = wr * 64 + mt * 16 + q * 4 + r;
            const float2 rd = *(const float2*)&red[row][0];
            const float inv = 1.0f / (rd.x + rd.y);
            const int trow = mt * 16 + q * 4 + r;
            #pragma unroll
            for (int nt = 0; nt < 2; ++nt) {
                const int col = wc * 32 + nt * 16 + l15;
                Ctx[qtile + trow * 64 + col] = bf16rne(ctx[mt][nt][r] * inv);
            }
        }
}

// ------------------------------------------------------------------
// oproj v3 (frozen from R7): single-pass Wo. Out = ctx @ WoH + bo.
// A from ctx tiles, BK=64, 32 KB LDS, XCD remap cpx=96.
// ------------------------------------------------------------------
__global__ __launch_bounds__(256, 4) void oproj(
    const unsigned short* __restrict__ Ctx,
    const unsigned short* __restrict__ WoH,
    const float* __restrict__ bo, float* __restrict__ out)
{
    __shared__ unsigned short As[8192];
    __shared__ unsigned short Bs[8192];

    const int tid  = threadIdx.x;
    const int lane = tid & 63;
    const int wv   = tid >> 6;
    const int wr   = wv >> 1, wc = wv & 1;
    const int q    = lane >> 4, l15 = lane & 15;

    const int s   = blockIdx.x + 6 * blockIdx.y;    // hw dispatch order
    const int lid = (s & 7) * 96 + (s >> 3);        // 768 wgs, cpx = 96
    const int n0  = (lid % 6) * 128;
    const int m0  = (lid / 6) * 128;

    const int srow   = tid >> 3;
    const int schunk = (tid & 7) ^ (srow & 7);

    char* ldsA = (char*)(&As[0]) + (wv << 10);
    char* ldsB = (char*)(&Bs[0]) + (wv << 10);

    f32x4 acc[4][4];
    #pragma unroll
    for (int i = 0; i < 4; ++i)
        #pragma unroll
        for (int j = 0; j < 4; ++j) acc[i][j] = 0;

    const int swz = (l15 & 7);

    for (int k0 = 0; k0 < H_DIM; k0 += 64) {
        const int h = k0 >> 6;   // BK=64 == head size: one head per k-iter
        #pragma unroll
        for (int i = 0; i < 4; ++i) {
            const int tok = m0 + i * 32 + srow;
            const long tile = ((long)(tok >> 9) * NHEADS + h) * 8 + ((tok >> 6) & 7);
            GLL16(Ctx + tile * 4096 + (long)(tok & 63) * 64 + schunk * 8, ldsA + i * 4096);
            GLL16(WoH + (long)(n0 + i * 32 + srow) * H_DIM + k0 + schunk * 8, ldsB + i * 4096);
        }
        __syncthreads();

        #pragma unroll
        for (int ks = 0; ks < 2; ++ks) {
            const int pc = ((ks * 4 + q) ^ swz) * 8;
            short8 ah[4], bh[4];
            #pragma unroll
            for (int t = 0; t < 4; ++t) {
                const int mr = wr * 64 + t * 16 + l15;
                ah[t] = *(const short8*)&As[mr * 64 + pc];
                const int nr = wc * 64 + t * 16 + l15;
                bh[t] = *(const short8*)&Bs[nr * 64 + pc];
            }
            #pragma unroll
            for (int mt = 0; mt < 4; ++mt)
                #pragma unroll
                for (int nt = 0; nt < 4; ++nt)
                    acc[mt][nt] = __builtin_amdgcn_mfma_f32_16x16x32_bf16(ah[mt], bh[nt], acc[mt][nt], 0, 0, 0);
        }
        __syncthreads();
    }

    #pragma unroll
    for (int nt = 0; nt < 4; ++nt) {
        const int col = n0 + wc * 64 + nt * 16 + l15;
        const float bcol = bo[col];
        #pragma unroll
        for (int mt = 0; mt < 4; ++mt) {
            const int rowB = m0 + wr * 64 + mt * 16 + q * 4;
            #pragma unroll
            for (int r = 0; r < 4; ++r)
                out[(long)(rowB + r) * H_DIM + col] = acc[mt][nt][r] + bcol;
        }
    }
}

extern "C" void kernel_launch(void* const* d_in, const int* in_sizes, int n_in,
                              void* d_out, int out_size, void* d_ws, size_t ws_size,
                              hipStream_t stream) {
    const float* X  = (const float*)d_in[0];
    const float* Wq = (const float*)d_in[1]; const float* bq = (const float*)d_in[2];
    const float* Wk = (const float*)d_in[3]; const float* bk = (const float*)d_in[4];
    const float* Wv = (const float*)d_in[5]; const float* bv = (const float*)d_in[6];
    const float* Wo = (const float*)d_in[7]; const float* bo = (const float*)d_in[8];

    unsigned short* wsu = (unsigned short*)d_ws;
    unsigned short* Qt  = wsu;                    // 12,582,912 (Q tiles bf16; ctx in place)
    unsigned short* Kp  = Qt + 12582912L;         // 12,582,912 (bf16 [bmh][p][d])
    unsigned short* Vp  = Kp + 12582912L;         // 12,582,912 (bf16 [bmh][d][p])
    unsigned short* Wt  = Vp + 12582912L;         // 4 planes x 589,824
    const long WP = (long)H_DIM * H_DIM;
    unsigned short* WqH = Wt;
    unsigned short* WkH = Wt + WP;
    unsigned short* WvH = Wt + 2 * WP;
    unsigned short* WoH = Wt + 3 * WP;

    // X~ lives in d_out (dead until oproj overwrites it)
    unsigned short* Xb = (unsigned short*)d_out;

    prep_all<<<6720, 256, 0, stream>>>(X, Xb, Wq, Wk, Wv, Wo,
                                       WqH, WkH, WvH, WoH);

    const float qscale = 0.125f * 1.4426950408889634f;   // softmax in base-2 domain
    qkv_gemm<<<dim3(1152), 256, 0, stream>>>(Xb, WqH, WkH, WvH,
                                             bq, bk, bv, qscale, Qt, Kp, Vp);

    attn2<<<dim3(4, 384), 256, 0, stream>>>(Qt, Kp, Vp, Qt);

    oproj<<<dim3(6, 128), 256, 0, stream>>>(Qt, WoH, bo, (float*)d_out);
}

// Round 11
// 290.362 us; speedup vs baseline: 1.0219x; 1.0219x over previous
//
#include <hip/hip_runtime.h>
#include <cstdint>
#include <cstddef>

#define H_DIM 768
#define NHEADS 12
#define HSZ 64
#define PATCH 512
#define MTOT 16384                 // 8*4*512 tokens
#define SZT ((long)MTOT * H_DIM)   // elements per [16384,768] matrix

using short8 = __attribute__((ext_vector_type(8))) short;   // 8 bf16 (4 VGPRs)
using f32x4  = __attribute__((ext_vector_type(4))) float;   // MFMA accumulator
using us4    = __attribute__((ext_vector_type(4))) unsigned short;

// async global->LDS, 16B per lane; LDS dest = wave-uniform base + lane*16
#define GLL16(gp, lp) __builtin_amdgcn_global_load_lds( \
    (const __attribute__((address_space(1))) void*)(gp), \
    (__attribute__((address_space(3))) void*)(lp), 16, 0, 0)

#define SB0() __builtin_amdgcn_sched_barrier(0)

__device__ __forceinline__ unsigned short bf16rne(float x) {
    unsigned v = __float_as_uint(x);
    v += 0x7fff + ((v >> 16) & 1);
    return (unsigned short)(v >> 16);
}

// ------------------------------------------------------------------
// prep_all: fused preprocessing in ONE launch.
// blocks [0,6144): X fp32 -> X~ bf16 RNE (8 elems/thread).
// blocks [6144,6720): 4 x 144 weight-transpose tiles (Wq,Wk,Wv,Wo -> bf16 RNE).
// ------------------------------------------------------------------
__global__ __launch_bounds__(256) void prep_all(
    const float* __restrict__ X, unsigned short* __restrict__ Xb,
    const float* __restrict__ Wq, const float* __restrict__ Wk,
    const float* __restrict__ Wv, const float* __restrict__ Wo,
    unsigned short* __restrict__ WqH, unsigned short* __restrict__ WkH,
    unsigned short* __restrict__ WvH, unsigned short* __restrict__ WoH)
{
    __shared__ float T[64][65];
    const int b = blockIdx.x;
    const int tid = threadIdx.x;

    if (b < 6144) {
        const long i = ((long)b * 256 + tid) * 8;
        float4 a = *(const float4*)&X[i];
        float4 c = *(const float4*)&X[i + 4];
        float xs[8] = {a.x, a.y, a.z, a.w, c.x, c.y, c.z, c.w};
        us4 h0, h1;
        #pragma unroll
        for (int j = 0; j < 4; ++j) { h0[j] = bf16rne(xs[j]); h1[j] = bf16rne(xs[j + 4]); }
        *(us4*)&Xb[i] = h0; *(us4*)&Xb[i + 4] = h1;
        return;
    }

    const int w     = b - 6144;
    const int which = w / 144;                 // 0=Wq 1=Wk 2=Wv 3=Wo
    const int t     = w % 144;
    const int kt    = (t / 12) * 64, nt = (t % 12) * 64;
    const float* W  = (which == 0) ? Wq : (which == 1) ? Wk : (which == 2) ? Wv : Wo;
    unsigned short* Whi = (which == 0) ? WqH : (which == 1) ? WkH : (which == 2) ? WvH : WoH;

    const int r = tid >> 2, c16 = (tid & 3) * 16;
    #pragma unroll
    for (int j = 0; j < 4; ++j) {
        float4 v = *(const float4*)&W[(long)(kt + r) * H_DIM + nt + c16 + j * 4];
        T[r][c16 + j*4 + 0] = v.x; T[r][c16 + j*4 + 1] = v.y;
        T[r][c16 + j*4 + 2] = v.z; T[r][c16 + j*4 + 3] = v.w;
    }
    __syncthreads();
    unsigned short* ph = &Whi[(long)(nt + r) * H_DIM + kt + c16];
    #pragma unroll
    for (int j = 0; j < 16; ++j)
        ph[j] = bf16rne(T[c16 + j][r]);
}

// ------------------------------------------------------------------
// qkv_gemm v4 (frozen from R6/R7, best timed total): block 256x128, 4 waves
// as 2M x 2N, per-wave 128x64 (acc[8][4]), BK=64, 48 KB LDS, grid 1152,
// XCD-bijective remap cpx=144. Vp stored LINEAR.
// rocprof replay durs distorted for this kernel (R6 lesson) — timed total only.
// ------------------------------------------------------------------
__global__ __launch_bounds__(256, 2) void qkv_gemm(
    const unsigned short* __restrict__ Xb,
    const unsigned short* __restrict__ WqH, const unsigned short* __restrict__ WkH,
    const unsigned short* __restrict__ WvH,
    const float* __restrict__ bq, const float* __restrict__ bk, const float* __restrict__ bv,
    float qscale,
    unsigned short* __restrict__ Qt, unsigned short* __restrict__ Kp,
    unsigned short* __restrict__ Vp)
{
    __shared__ unsigned short As[16384];     // 256 rows x 64 k (swizzled chunks)
    __shared__ unsigned short Bs[8192];      // 128 rows x 64 k

    const int s   = blockIdx.x;                     // 0..1151, hw dispatch order
    const int lid = (s & 7) * 144 + (s >> 3);       // bijective, 1152 = 8*144
    const int bx  = lid % 18;
    const int by  = lid / 18;                       // 0..63

    const int mat = bx / 6;
    const int n0  = (bx % 6) * 128;
    const int m0  = by * 256;
    const unsigned short* Bh = (mat == 0) ? WqH : (mat == 1) ? WkH : WvH;
    const float* bias        = (mat == 0) ? bq  : (mat == 1) ? bk  : bv;
    const float scale        = (mat == 0) ? qscale : 1.0f;

    const int tid  = threadIdx.x;
    const int lane = tid & 63;
    const int wv   = tid >> 6;
    const int wr   = wv >> 1, wc = wv & 1;
    const int q    = lane >> 4, l15 = lane & 15;

    const int srow   = tid >> 3;                        // 0..31
    const int schunk = (tid & 7) ^ (srow & 7);          // swizzled global chunk

    char* ldsA = (char*)(&As[0]) + (wv << 10);
    char* ldsB = (char*)(&Bs[0]) + (wv << 10);

    f32x4 acc[8][4];
    #pragma unroll
    for (int i = 0; i < 8; ++i)
        #pragma unroll
        for (int j = 0; j < 4; ++j) acc[i][j] = 0;

    const int swz = (l15 & 7);   // row-dependent chunk swizzle for fragment reads

    for (int k0 = 0; k0 < H_DIM; k0 += 64) {
        #pragma unroll
        for (int i = 0; i < 8; ++i)
            GLL16(Xb + (long)(m0 + i * 32 + srow) * H_DIM + k0 + schunk * 8,
                  ldsA + i * 4096);
        #pragma unroll
        for (int i = 0; i < 4; ++i)
            GLL16(Bh + (long)(n0 + i * 32 + srow) * H_DIM + k0 + schunk * 8,
                  ldsB + i * 4096);
        __syncthreads();

        #pragma unroll
        for (int ks = 0; ks < 2; ++ks) {
            const int pc = ((ks * 4 + q) ^ swz) * 8;
            short8 ah[8], bh[4];
            #pragma unroll
            for (int t = 0; t < 8; ++t) {
                const int mr = wr * 128 + t * 16 + l15;
                ah[t] = *(const short8*)&As[mr * 64 + pc];
            }
            #pragma unroll
            for (int t = 0; t < 4; ++t) {
                const int nr = wc * 64 + t * 16 + l15;
                bh[t] = *(const short8*)&Bs[nr * 64 + pc];
            }
            #pragma unroll
            for (int mt = 0; mt < 8; ++mt)
                #pragma unroll
                for (int nt = 0; nt < 4; ++nt)
                    acc[mt][nt] = __builtin_amdgcn_mfma_f32_16x16x32_bf16(ah[mt], bh[nt], acc[mt][nt], 0, 0, 0);
        }
        __syncthreads();
    }

    // epilogue: C/D layout col = lane&15, row = quad*4 + reg
    #pragma unroll
    for (int nt = 0; nt < 4; ++nt) {
        const int col = n0 + wc * 64 + nt * 16 + l15;
        const float bcol = bias[col];
        const int h = col >> 6, d = col & 63;
        #pragma unroll
        for (int mt = 0; mt < 8; ++mt) {
            const int rowB = m0 + wr * 128 + mt * 16 + q * 4;
            #pragma unroll
            for (int r = 0; r < 4; ++r) {
                const int row = rowB + r;
                const float val = (acc[mt][nt][r] + bcol) * scale;
                const int bm = row >> 9, p = row & 511;
                const int bmh = bm * NHEADS + h;
                if (mat == 0) {
                    const long idx = ((long)bmh * 8 + (p >> 6)) * 4096 + (long)(p & 63) * 64 + d;
                    Qt[idx] = bf16rne(val);
                } else if (mat == 1) {
                    Kp[(long)bmh * 32768 + (long)p * 64 + d] = bf16rne(val);
                } else {
                    Vp[(long)bmh * 32768 + (long)d * 512 + p] = bf16rne(val);
                }
            }
        }
    }
}

// ------------------------------------------------------------------
// attn2 (restored R7 version — best measured: async double-buffered K/V
// staging, counted vmcnt(4), raw s_barrier; R10 A/B proved this beats sync
// staging at 4 blocks/CU by ~16us). LDS 51.4 KB, 3 blocks/CU.
// ------------------------------------------------------------------
__global__ __launch_bounds__(256, 3) void attn2(
    const unsigned short* __restrict__ Qt,
    const unsigned short* __restrict__ Kp, const unsigned short* __restrict__ Vp,
    unsigned short* __restrict__ Ctx)
{
    __shared__ unsigned short Ks[2][4096];   // dbuf [key][swz-chunk*8] bf16
    __shared__ unsigned short Vs[2][4096];   // dbuf [d][swz-chunk*8] bf16
    __shared__ unsigned short Ps[128 * 72];  // P bf16, padded stride 72
    __shared__ float red[128][2];            // cross-wave row sum (finalize)

    const int tid  = threadIdx.x;
    const int lane = tid & 63;
    const int wv   = tid >> 6;
    const int wr   = wv >> 1, wc = wv & 1;
    const int q    = lane >> 4, l15 = lane & 15;

    const int s   = blockIdx.x + 4 * blockIdx.y;    // hw dispatch order
    const int lid = (s & 7) * 192 + (s >> 3);       // 1536 wgs, cpx = 192
    const int qt2 = lid & 3;     // 0..3
    const int bmh = lid >> 2;    // 0..383

    // ---- Q fragments (loop-invariant) ----
    short8 qh[4][2];
    const long qtile = ((long)bmh * 8 + qt2 * 2 + wr) * 4096;
    #pragma unroll
    for (int mt = 0; mt < 4; ++mt)
        #pragma unroll
        for (int ks = 0; ks < 2; ++ks)
            qh[mt][ks] = *(const short8*)&Qt[qtile + (mt * 16 + l15) * 64 + ks * 32 + q * 8];

    f32x4 ctx[4][2];
    float l_cur[4][4];
    #pragma unroll
    for (int mt = 0; mt < 4; ++mt) {
        ctx[mt][0] = 0; ctx[mt][1] = 0;
        #pragma unroll
        for (int r = 0; r < 4; ++r) l_cur[mt][r] = 0.0f;
    }

    const long khead = (long)bmh * 32768;
    const int srow   = tid >> 3;                               // 0..31
    const int gchunk = ((tid & 7) ^ (srow & 7)) * 8;           // swizzled source chunk
    char* dK = (char*)&Ks[0][0] + (wv << 10);
    char* dV = (char*)&Vs[0][0] + (wv << 10);

    // stage tile kt_ into buffer bsel (4 GLL16/thread, wave-linear LDS dest)
    #define STAGE_KV(kt_, bsel) do { \
        const long kb_ = khead + (long)(kt_) * 64 * 64; \
        GLL16(Kp + kb_ + (long)srow * 64 + gchunk,        dK + (bsel) * 8192); \
        GLL16(Kp + kb_ + (long)(srow + 32) * 64 + gchunk, dK + (bsel) * 8192 + 4096); \
        const long vb_ = khead + (long)(kt_) * 64; \
        GLL16(Vp + vb_ + (long)srow * 512 + gchunk,        dV + (bsel) * 8192); \
        GLL16(Vp + vb_ + (long)(srow + 32) * 512 + gchunk, dV + (bsel) * 8192 + 4096); \
    } while (0)

    STAGE_KV(0, 0);   // prologue: tile 0 in flight

    #pragma unroll 1
    for (int kt = 0; kt < 8; ++kt) {
        const int cur = kt & 1;
        // barrier 1: all waves' ds_reads of buf[cur^1] (prev iter) retired
        asm volatile("s_waitcnt lgkmcnt(0)" ::: "memory");
        SB0();
        __builtin_amdgcn_s_barrier();
        if (kt < 7) {
            STAGE_KV(kt + 1, cur ^ 1);                         // issue early
            asm volatile("s_waitcnt vmcnt(4)" ::: "memory");   // tile kt landed (mine)
        } else {
            asm volatile("s_waitcnt vmcnt(0)" ::: "memory");   // last tile: drain
        }
        SB0();
        __builtin_amdgcn_s_barrier();   // barrier 2: tile kt landed for ALL waves

        // ---- S = Q K^T (1-pass) : rows wr*64+, keys wc*32+ ----
        f32x4 sv[4][2];
        #pragma unroll
        for (int mt = 0; mt < 4; ++mt) { sv[mt][0] = 0; sv[mt][1] = 0; }
        short8 kf[2][2];
        #pragma unroll
        for (int nt = 0; nt < 2; ++nt)
            #pragma unroll
            for (int ks = 0; ks < 2; ++ks) {
                const int key = wc * 32 + nt * 16 + l15;
                const int phys = (q + ks * 4) ^ (key & 7);
                kf[nt][ks] = *(const short8*)&Ks[cur][key * 64 + phys * 8];
            }
        #pragma unroll
        for (int mt = 0; mt < 4; ++mt)
            #pragma unroll
            for (int nt = 0; nt < 2; ++nt)
                #pragma unroll
                for (int ks = 0; ks < 2; ++ks)
                    sv[mt][nt] = __builtin_amdgcn_mfma_f32_16x16x32_bf16(qh[mt][ks], kf[nt][ks], sv[mt][nt], 0, 0, 0);

        // ---- p = exp2(s); accumulate l; write P bf16 ----
        #pragma unroll
        for (int mt = 0; mt < 4; ++mt)
            #pragma unroll
            for (int r = 0; r < 4; ++r) {
                const int row = wr * 64 + mt * 16 + q * 4 + r;
                const float p0 = __builtin_amdgcn_exp2f(sv[mt][0][r]);
                const float p1 = __builtin_amdgcn_exp2f(sv[mt][1][r]);
                l_cur[mt][r] += p0 + p1;
                Ps[row * 72 + wc * 32 + l15]      = bf16rne(p0);
                Ps[row * 72 + wc * 32 + 16 + l15] = bf16rne(p1);
            }
        asm volatile("s_waitcnt lgkmcnt(0)" ::: "memory");   // my Ps writes landed
        SB0();
        __builtin_amdgcn_s_barrier();   // barrier 3: Ps ready

        // ---- ctx += P V (1-pass) : rows wr*64+, d-cols wc*32+ ----
        short8 pf[4][2], vf[2][2];
        #pragma unroll
        for (int mt = 0; mt < 4; ++mt)
            #pragma unroll
            for (int ks = 0; ks < 2; ++ks)
                pf[mt][ks] = *(const short8*)&Ps[(wr * 64 + mt * 16 + l15) * 72 + ks * 32 + q * 8];
        #pragma unroll
        for (int nt = 0; nt < 2; ++nt)
            #pragma unroll
            for (int ks = 0; ks < 2; ++ks) {
                const int d = wc * 32 + nt * 16 + l15;
                const int phys = (q + ks * 4) ^ (d & 7);
                vf[nt][ks] = *(const short8*)&Vs[cur][d * 64 + phys * 8];
            }
        #pragma unroll
        for (int mt = 0; mt < 4; ++mt)
            #pragma unroll
            for (int nt = 0; nt < 2; ++nt)
                #pragma unroll
                for (int ks = 0; ks < 2; ++ks)
                    ctx[mt][nt] = __builtin_amdgcn_mfma_f32_16x16x32_bf16(pf[mt][ks], vf[nt][ks], ctx[mt][nt], 0, 0, 0);
    }
    #undef STAGE_KV

    // ---- finalize l (in-quad + cross-wave sum), normalize, store ctx bf16 ----
    #pragma unroll
    for (int mt = 0; mt < 4; ++mt)
        #pragma unroll
        for (int r = 0; r < 4; ++r) {
            float v = l_cur[mt][r];
            v += __shfl_xor(v, 1);
            v += __shfl_xor(v, 2);
            v += __shfl_xor(v, 4);
            v += __shfl_xor(v, 8);
            if (l15 == 0) red[wr * 64 + mt * 16 + q * 4 + r][wc] = v;
        }
    __syncthreads();
    #pragma unroll
    for (int mt = 0; mt < 4; ++mt)
        #pragma unroll
        for (int r = 0; r < 4; ++r) {
            const int row = wr * 64 + mt * 16 + q * 4 + r;
            const float2 rd = *(const float2*)&red[row][0];
            const float inv = 1.0f / (rd.x + rd.y);
            const int trow = mt * 16 + q * 4 + r;
            #pragma unroll
            for (int nt = 0; nt < 2; ++nt) {
                const int col = wc * 32 + nt * 16 + l15;
                Ctx[qtile + trow * 64 + col] = bf16rne(ctx[mt][nt][r] * inv);
            }
        }
}

// ------------------------------------------------------------------
// oproj v4 (R11): FAT TILE — same transform that won on qkv (R6).
// Block 256x128, 4 waves as 2M x 2N, per-wave 128x64 (acc[8][4]), BK=64.
// Per-output LDS reads and staged bytes both -25% vs 128x128.
// Grid 384 (fully co-resident at <=3/CU), XCD-bijective remap cpx=48.
// Single-pass Wo. Numerics bit-identical to R7's oproj (same k-order).
// ------------------------------------------------------------------
__global__ __launch_bounds__(256, 2) void oproj(
    const unsigned short* __restrict__ Ctx,
    const unsigned short* __restrict__ WoH,
    const float* __restrict__ bo, float* __restrict__ out)
{
    __shared__ unsigned short As[16384];   // 256 tok x 64 k (swizzled chunks)
    __shared__ unsigned short Bs[8192];    // 128 cols x 64 k

    const int tid  = threadIdx.x;
    const int lane = tid & 63;
    const int wv   = tid >> 6;
    const int wr   = wv >> 1, wc = wv & 1;
    const int q    = lane >> 4, l15 = lane & 15;

    const int s   = blockIdx.x;                 // 0..383
    const int lid = (s & 7) * 48 + (s >> 3);    // bijective, 384 = 8*48
    const int n0  = (lid % 6) * 128;
    const int m0  = (lid / 6) * 256;

    const int srow   = tid >> 3;
    const int schunk = (tid & 7) ^ (srow & 7);

    char* ldsA = (char*)(&As[0]) + (wv << 10);
    char* ldsB = (char*)(&Bs[0]) + (wv << 10);

    f32x4 acc[8][4];
    #pragma unroll
    for (int i = 0; i < 8; ++i)
        #pragma unroll
        for (int j = 0; j < 4; ++j) acc[i][j] = 0;

    const int swz = (l15 & 7);

    for (int k0 = 0; k0 < H_DIM; k0 += 64) {
        const int h = k0 >> 6;   // BK=64 == head size: one head per k-iter
        #pragma unroll
        for (int i = 0; i < 8; ++i) {
            const int tok = m0 + i * 32 + srow;
            const long tile = ((long)(tok >> 9) * NHEADS + h) * 8 + ((tok >> 6) & 7);
            GLL16(Ctx + tile * 4096 + (long)(tok & 63) * 64 + schunk * 8, ldsA + i * 4096);
        }
        #pragma unroll
        for (int i = 0; i < 4; ++i)
            GLL16(WoH + (long)(n0 + i * 32 + srow) * H_DIM + k0 + schunk * 8, ldsB + i * 4096);
        __syncthreads();

        #pragma unroll
        for (int ks = 0; ks < 2; ++ks) {
            const int pc = ((ks * 4 + q) ^ swz) * 8;
            short8 ah[8], bh[4];
            #pragma unroll
            for (int t = 0; t < 8; ++t) {
                const int mr = wr * 128 + t * 16 + l15;
                ah[t] = *(const short8*)&As[mr * 64 + pc];
            }
            #pragma unroll
            for (int t = 0; t < 4; ++t) {
                const int nr = wc * 64 + t * 16 + l15;
                bh[t] = *(const short8*)&Bs[nr * 64 + pc];
            }
            #pragma unroll
            for (int mt = 0; mt < 8; ++mt)
                #pragma unroll
                for (int nt = 0; nt < 4; ++nt)
                    acc[mt][nt] = __builtin_amdgcn_mfma_f32_16x16x32_bf16(ah[mt], bh[nt], acc[mt][nt], 0, 0, 0);
        }
        __syncthreads();
    }

    #pragma unroll
    for (int nt = 0; nt < 4; ++nt) {
        const int col = n0 + wc * 64 + nt * 16 + l15;
        const float bcol = bo[col];
        #pragma unroll
        for (int mt = 0; mt < 8; ++mt) {
            const int rowB = m0 + wr * 128 + mt * 16 + q * 4;
            #pragma unroll
            for (int r = 0; r < 4; ++r)
                out[(long)(rowB + r) * H_DIM + col] = acc[mt][nt][r] + bcol;
        }
    }
}

extern "C" void kernel_launch(void* const* d_in, const int* in_sizes, int n_in,
                              void* d_out, int out_size, void* d_ws, size_t ws_size,
                              hipStream_t stream) {
    const float* X  = (const float*)d_in[0];
    const float* Wq = (const float*)d_in[1]; const float* bq = (const float*)d_in[2];
    const float* Wk = (const float*)d_in[3]; const float* bk = (const float*)d_in[4];
    const float* Wv = (const float*)d_in[5]; const float* bv = (const float*)d_in[6];
    const float* Wo = (const float*)d_in[7]; const float* bo = (const float*)d_in[8];

    unsigned short* wsu = (unsigned short*)d_ws;
    unsigned short* Qt  = wsu;                    // 12,582,912 (Q tiles bf16; ctx in place)
    unsigned short* Kp  = Qt + 12582912L;         // 12,582,912 (bf16 [bmh][p][d])
    unsigned short* Vp  = Kp + 12582912L;         // 12,582,912 (bf16 [bmh][d][p])
    unsigned short* Wt  = Vp + 12582912L;         // 4 planes x 589,824
    const long WP = (long)H_DIM * H_DIM;
    unsigned short* WqH = Wt;
    unsigned short* WkH = Wt + WP;
    unsigned short* WvH = Wt + 2 * WP;
    unsigned short* WoH = Wt + 3 * WP;

    // X~ lives in d_out (dead until oproj overwrites it)
    unsigned short* Xb = (unsigned short*)d_out;

    prep_all<<<6720, 256, 0, stream>>>(X, Xb, Wq, Wk, Wv, Wo,
                                       WqH, WkH, WvH, WoH);

    const float qscale = 0.125f * 1.4426950408889634f;   // softmax in base-2 domain
    qkv_gemm<<<dim3(1152), 256, 0, stream>>>(Xb, WqH, WkH, WvH,
                                             bq, bk, bv, qscale, Qt, Kp, Vp);

    attn2<<<dim3(4, 384), 256, 0, stream>>>(Qt, Kp, Vp, Qt);

    oproj<<<dim3(384), 256, 0, stream>>>(Qt, WoH, bo, (float*)d_out);
}

// Round 12
// 275.209 us; speedup vs baseline: 1.0782x; 1.0551x over previous
//
#include <hip/hip_runtime.h>
#include <cstdint>
#include <cstddef>

#define H_DIM 768
#define NHEADS 12
#define HSZ 64
#define PATCH 512
#define MTOT 16384                 // 8*4*512 tokens
#define SZT ((long)MTOT * H_DIM)   // elements per [16384,768] matrix

using short8 = __attribute__((ext_vector_type(8))) short;   // 8 bf16 (4 VGPRs)
using f32x4  = __attribute__((ext_vector_type(4))) float;   // MFMA accumulator
using us4    = __attribute__((ext_vector_type(4))) unsigned short;

// async global->LDS, 16B per lane; LDS dest = wave-uniform base + lane*16
#define GLL16(gp, lp) __builtin_amdgcn_global_load_lds( \
    (const __attribute__((address_space(1))) void*)(gp), \
    (__attribute__((address_space(3))) void*)(lp), 16, 0, 0)

#define SB0() __builtin_amdgcn_sched_barrier(0)

__device__ __forceinline__ unsigned short bf16rne(float x) {
    unsigned v = __float_as_uint(x);
    v += 0x7fff + ((v >> 16) & 1);
    return (unsigned short)(v >> 16);
}

// ------------------------------------------------------------------
// prep_all: fused preprocessing in ONE launch.
// blocks [0,6144): X fp32 -> X~ bf16 RNE (8 elems/thread).
// blocks [6144,6720): 4 x 144 weight-transpose tiles (Wq,Wk,Wv,Wo -> bf16 RNE).
// ------------------------------------------------------------------
__global__ __launch_bounds__(256) void prep_all(
    const float* __restrict__ X, unsigned short* __restrict__ Xb,
    const float* __restrict__ Wq, const float* __restrict__ Wk,
    const float* __restrict__ Wv, const float* __restrict__ Wo,
    unsigned short* __restrict__ WqH, unsigned short* __restrict__ WkH,
    unsigned short* __restrict__ WvH, unsigned short* __restrict__ WoH)
{
    __shared__ float T[64][65];
    const int b = blockIdx.x;
    const int tid = threadIdx.x;

    if (b < 6144) {
        const long i = ((long)b * 256 + tid) * 8;
        float4 a = *(const float4*)&X[i];
        float4 c = *(const float4*)&X[i + 4];
        float xs[8] = {a.x, a.y, a.z, a.w, c.x, c.y, c.z, c.w};
        us4 h0, h1;
        #pragma unroll
        for (int j = 0; j < 4; ++j) { h0[j] = bf16rne(xs[j]); h1[j] = bf16rne(xs[j + 4]); }
        *(us4*)&Xb[i] = h0; *(us4*)&Xb[i + 4] = h1;
        return;
    }

    const int w     = b - 6144;
    const int which = w / 144;                 // 0=Wq 1=Wk 2=Wv 3=Wo
    const int t     = w % 144;
    const int kt    = (t / 12) * 64, nt = (t % 12) * 64;
    const float* W  = (which == 0) ? Wq : (which == 1) ? Wk : (which == 2) ? Wv : Wo;
    unsigned short* Whi = (which == 0) ? WqH : (which == 1) ? WkH : (which == 2) ? WvH : WoH;

    const int r = tid >> 2, c16 = (tid & 3) * 16;
    #pragma unroll
    for (int j = 0; j < 4; ++j) {
        float4 v = *(const float4*)&W[(long)(kt + r) * H_DIM + nt + c16 + j * 4];
        T[r][c16 + j*4 + 0] = v.x; T[r][c16 + j*4 + 1] = v.y;
        T[r][c16 + j*4 + 2] = v.z; T[r][c16 + j*4 + 3] = v.w;
    }
    __syncthreads();
    unsigned short* ph = &Whi[(long)(nt + r) * H_DIM + kt + c16];
    #pragma unroll
    for (int j = 0; j < 16; ++j)
        ph[j] = bf16rne(T[c16 + j][r]);
}

// ------------------------------------------------------------------
// qkv_gemm v5 (R12): R6/R7 structure + PACKED V-EPILOGUE.
// Block 256x128, 4 waves as 2M x 2N, per-wave 128x64 (acc[8][4]), BK=64,
// 48 KB LDS, grid 1152, XCD-bijective remap cpx=144.
// V-transpose store: acc r=0..3 map to CONTIGUOUS p in Vp[d][p] -> pack
// into one aligned 8B us4 store (32 scalar 2B stores -> 8x 8B; 4x fewer
// partial-line fragments, better L2 write-combining). Values bit-identical.
// rocprof replay durs distorted for this kernel (R6 lesson) — timed total only.
// ------------------------------------------------------------------
__global__ __launch_bounds__(256, 2) void qkv_gemm(
    const unsigned short* __restrict__ Xb,
    const unsigned short* __restrict__ WqH, const unsigned short* __restrict__ WkH,
    const unsigned short* __restrict__ WvH,
    const float* __restrict__ bq, const float* __restrict__ bk, const float* __restrict__ bv,
    float qscale,
    unsigned short* __restrict__ Qt, unsigned short* __restrict__ Kp,
    unsigned short* __restrict__ Vp)
{
    __shared__ unsigned short As[16384];     // 256 rows x 64 k (swizzled chunks)
    __shared__ unsigned short Bs[8192];      // 128 rows x 64 k

    const int s   = blockIdx.x;                     // 0..1151, hw dispatch order
    const int lid = (s & 7) * 144 + (s >> 3);       // bijective, 1152 = 8*144
    const int bx  = lid % 18;
    const int by  = lid / 18;                       // 0..63

    const int mat = bx / 6;
    const int n0  = (bx % 6) * 128;
    const int m0  = by * 256;
    const unsigned short* Bh = (mat == 0) ? WqH : (mat == 1) ? WkH : WvH;
    const float* bias        = (mat == 0) ? bq  : (mat == 1) ? bk  : bv;
    const float scale        = (mat == 0) ? qscale : 1.0f;

    const int tid  = threadIdx.x;
    const int lane = tid & 63;
    const int wv   = tid >> 6;
    const int wr   = wv >> 1, wc = wv & 1;
    const int q    = lane >> 4, l15 = lane & 15;

    const int srow   = tid >> 3;                        // 0..31
    const int schunk = (tid & 7) ^ (srow & 7);          // swizzled global chunk

    char* ldsA = (char*)(&As[0]) + (wv << 10);
    char* ldsB = (char*)(&Bs[0]) + (wv << 10);

    f32x4 acc[8][4];
    #pragma unroll
    for (int i = 0; i < 8; ++i)
        #pragma unroll
        for (int j = 0; j < 4; ++j) acc[i][j] = 0;

    const int swz = (l15 & 7);   // row-dependent chunk swizzle for fragment reads

    for (int k0 = 0; k0 < H_DIM; k0 += 64) {
        #pragma unroll
        for (int i = 0; i < 8; ++i)
            GLL16(Xb + (long)(m0 + i * 32 + srow) * H_DIM + k0 + schunk * 8,
                  ldsA + i * 4096);
        #pragma unroll
        for (int i = 0; i < 4; ++i)
            GLL16(Bh + (long)(n0 + i * 32 + srow) * H_DIM + k0 + schunk * 8,
                  ldsB + i * 4096);
        __syncthreads();

        #pragma unroll
        for (int ks = 0; ks < 2; ++ks) {
            const int pc = ((ks * 4 + q) ^ swz) * 8;
            short8 ah[8], bh[4];
            #pragma unroll
            for (int t = 0; t < 8; ++t) {
                const int mr = wr * 128 + t * 16 + l15;
                ah[t] = *(const short8*)&As[mr * 64 + pc];
            }
            #pragma unroll
            for (int t = 0; t < 4; ++t) {
                const int nr = wc * 64 + t * 16 + l15;
                bh[t] = *(const short8*)&Bs[nr * 64 + pc];
            }
            #pragma unroll
            for (int mt = 0; mt < 8; ++mt)
                #pragma unroll
                for (int nt = 0; nt < 4; ++nt)
                    acc[mt][nt] = __builtin_amdgcn_mfma_f32_16x16x32_bf16(ah[mt], bh[nt], acc[mt][nt], 0, 0, 0);
        }
        __syncthreads();
    }

    // epilogue: C/D layout col = lane&15, row = quad*4 + reg
    #pragma unroll
    for (int nt = 0; nt < 4; ++nt) {
        const int col = n0 + wc * 64 + nt * 16 + l15;
        const float bcol = bias[col];
        const int h = col >> 6, d = col & 63;
        #pragma unroll
        for (int mt = 0; mt < 8; ++mt) {
            const int rowB = m0 + wr * 128 + mt * 16 + q * 4;
            if (mat == 2) {
                // V: r=0..3 -> contiguous p at fixed d. Pack 4 bf16 -> 8B store.
                const int bmh = (rowB >> 9) * NHEADS + h;
                const int p0  = rowB & 511;          // multiple of 4 -> 8B aligned
                us4 pk;
                #pragma unroll
                for (int r = 0; r < 4; ++r)
                    pk[r] = bf16rne((acc[mt][nt][r] + bcol) * scale);
                *(us4*)&Vp[(long)bmh * 32768 + (long)d * 512 + p0] = pk;
            } else {
                #pragma unroll
                for (int r = 0; r < 4; ++r) {
                    const int row = rowB + r;
                    const float val = (acc[mt][nt][r] + bcol) * scale;
                    const int bm = row >> 9, p = row & 511;
                    const int bmh = bm * NHEADS + h;
                    if (mat == 0) {
                        const long idx = ((long)bmh * 8 + (p >> 6)) * 4096 + (long)(p & 63) * 64 + d;
                        Qt[idx] = bf16rne(val);
                    } else {
                        Kp[(long)bmh * 32768 + (long)p * 64 + d] = bf16rne(val);
                    }
                }
            }
        }
    }
}

// ------------------------------------------------------------------
// attn2 (frozen R7 version — best measured: async double-buffered K/V
// staging, counted vmcnt(4), raw s_barrier; R10 A/B proved this beats sync
// staging at 4 blocks/CU by ~16us). LDS 51.4 KB, 3 blocks/CU.
// ------------------------------------------------------------------
__global__ __launch_bounds__(256, 3) void attn2(
    const unsigned short* __restrict__ Qt,
    const unsigned short* __restrict__ Kp, const unsigned short* __restrict__ Vp,
    unsigned short* __restrict__ Ctx)
{
    __shared__ unsigned short Ks[2][4096];   // dbuf [key][swz-chunk*8] bf16
    __shared__ unsigned short Vs[2][4096];   // dbuf [d][swz-chunk*8] bf16
    __shared__ unsigned short Ps[128 * 72];  // P bf16, padded stride 72
    __shared__ float red[128][2];            // cross-wave row sum (finalize)

    const int tid  = threadIdx.x;
    const int lane = tid & 63;
    const int wv   = tid >> 6;
    const int wr   = wv >> 1, wc = wv & 1;
    const int q    = lane >> 4, l15 = lane & 15;

    const int s   = blockIdx.x + 4 * blockIdx.y;    // hw dispatch order
    const int lid = (s & 7) * 192 + (s >> 3);       // 1536 wgs, cpx = 192
    const int qt2 = lid & 3;     // 0..3
    const int bmh = lid >> 2;    // 0..383

    // ---- Q fragments (loop-invariant) ----
    short8 qh[4][2];
    const long qtile = ((long)bmh * 8 + qt2 * 2 + wr) * 4096;
    #pragma unroll
    for (int mt = 0; mt < 4; ++mt)
        #pragma unroll
        for (int ks = 0; ks < 2; ++ks)
            qh[mt][ks] = *(const short8*)&Qt[qtile + (mt * 16 + l15) * 64 + ks * 32 + q * 8];

    f32x4 ctx[4][2];
    float l_cur[4][4];
    #pragma unroll
    for (int mt = 0; mt < 4; ++mt) {
        ctx[mt][0] = 0; ctx[mt][1] = 0;
        #pragma unroll
        for (int r = 0; r < 4; ++r) l_cur[mt][r] = 0.0f;
    }

    const long khead = (long)bmh * 32768;
    const int srow   = tid >> 3;                               // 0..31
    const int gchunk = ((tid & 7) ^ (srow & 7)) * 8;           // swizzled source chunk
    char* dK = (char*)&Ks[0][0] + (wv << 10);
    char* dV = (char*)&Vs[0][0] + (wv << 10);

    // stage tile kt_ into buffer bsel (4 GLL16/thread, wave-linear LDS dest)
    #define STAGE_KV(kt_, bsel) do { \
        const long kb_ = khead + (long)(kt_) * 64 * 64; \
        GLL16(Kp + kb_ + (long)srow * 64 + gchunk,        dK + (bsel) * 8192); \
        GLL16(Kp + kb_ + (long)(srow + 32) * 64 + gchunk, dK + (bsel) * 8192 + 4096); \
        const long vb_ = khead + (long)(kt_) * 64; \
        GLL16(Vp + vb_ + (long)srow * 512 + gchunk,        dV + (bsel) * 8192); \
        GLL16(Vp + vb_ + (long)(srow + 32) * 512 + gchunk, dV + (bsel) * 8192 + 4096); \
    } while (0)

    STAGE_KV(0, 0);   // prologue: tile 0 in flight

    #pragma unroll 1
    for (int kt = 0; kt < 8; ++kt) {
        const int cur = kt & 1;
        // barrier 1: all waves' ds_reads of buf[cur^1] (prev iter) retired
        asm volatile("s_waitcnt lgkmcnt(0)" ::: "memory");
        SB0();
        __builtin_amdgcn_s_barrier();
        if (kt < 7) {
            STAGE_KV(kt + 1, cur ^ 1);                         // issue early
            asm volatile("s_waitcnt vmcnt(4)" ::: "memory");   // tile kt landed (mine)
        } else {
            asm volatile("s_waitcnt vmcnt(0)" ::: "memory");   // last tile: drain
        }
        SB0();
        __builtin_amdgcn_s_barrier();   // barrier 2: tile kt landed for ALL waves

        // ---- S = Q K^T (1-pass) : rows wr*64+, keys wc*32+ ----
        f32x4 sv[4][2];
        #pragma unroll
        for (int mt = 0; mt < 4; ++mt) { sv[mt][0] = 0; sv[mt][1] = 0; }
        short8 kf[2][2];
        #pragma unroll
        for (int nt = 0; nt < 2; ++nt)
            #pragma unroll
            for (int ks = 0; ks < 2; ++ks) {
                const int key = wc * 32 + nt * 16 + l15;
                const int phys = (q + ks * 4) ^ (key & 7);
                kf[nt][ks] = *(const short8*)&Ks[cur][key * 64 + phys * 8];
            }
        #pragma unroll
        for (int mt = 0; mt < 4; ++mt)
            #pragma unroll
            for (int nt = 0; nt < 2; ++nt)
                #pragma unroll
                for (int ks = 0; ks < 2; ++ks)
                    sv[mt][nt] = __builtin_amdgcn_mfma_f32_16x16x32_bf16(qh[mt][ks], kf[nt][ks], sv[mt][nt], 0, 0, 0);

        // ---- p = exp2(s); accumulate l; write P bf16 ----
        #pragma unroll
        for (int mt = 0; mt < 4; ++mt)
            #pragma unroll
            for (int r = 0; r < 4; ++r) {
                const int row = wr * 64 + mt * 16 + q * 4 + r;
                const float p0 = __builtin_amdgcn_exp2f(sv[mt][0][r]);
                const float p1 = __builtin_amdgcn_exp2f(sv[mt][1][r]);
                l_cur[mt][r] += p0 + p1;
                Ps[row * 72 + wc * 32 + l15]      = bf16rne(p0);
                Ps[row * 72 + wc * 32 + 16 + l15] = bf16rne(p1);
            }
        asm volatile("s_waitcnt lgkmcnt(0)" ::: "memory");   // my Ps writes landed
        SB0();
        __builtin_amdgcn_s_barrier();   // barrier 3: Ps ready

        // ---- ctx += P V (1-pass) : rows wr*64+, d-cols wc*32+ ----
        short8 pf[4][2], vf[2][2];
        #pragma unroll
        for (int mt = 0; mt < 4; ++mt)
            #pragma unroll
            for (int ks = 0; ks < 2; ++ks)
                pf[mt][ks] = *(const short8*)&Ps[(wr * 64 + mt * 16 + l15) * 72 + ks * 32 + q * 8];
        #pragma unroll
        for (int nt = 0; nt < 2; ++nt)
            #pragma unroll
            for (int ks = 0; ks < 2; ++ks) {
                const int d = wc * 32 + nt * 16 + l15;
                const int phys = (q + ks * 4) ^ (d & 7);
                vf[nt][ks] = *(const short8*)&Vs[cur][d * 64 + phys * 8];
            }
        #pragma unroll
        for (int mt = 0; mt < 4; ++mt)
            #pragma unroll
            for (int nt = 0; nt < 2; ++nt)
                #pragma unroll
                for (int ks = 0; ks < 2; ++ks)
                    ctx[mt][nt] = __builtin_amdgcn_mfma_f32_16x16x32_bf16(pf[mt][ks], vf[nt][ks], ctx[mt][nt], 0, 0, 0);
    }
    #undef STAGE_KV

    // ---- finalize l (in-quad + cross-wave sum), normalize, store ctx bf16 ----
    #pragma unroll
    for (int mt = 0; mt < 4; ++mt)
        #pragma unroll
        for (int r = 0; r < 4; ++r) {
            float v = l_cur[mt][r];
            v += __shfl_xor(v, 1);
            v += __shfl_xor(v, 2);
            v += __shfl_xor(v, 4);
            v += __shfl_xor(v, 8);
            if (l15 == 0) red[wr * 64 + mt * 16 + q * 4 + r][wc] = v;
        }
    __syncthreads();
    #pragma unroll
    for (int mt = 0; mt < 4; ++mt)
        #pragma unroll
        for (int r = 0; r < 4; ++r) {
            const int row = wr * 64 + mt * 16 + q * 4 + r;
            const float2 rd = *(const float2*)&red[row][0];
            const float inv = 1.0f / (rd.x + rd.y);
            const int trow = mt * 16 + q * 4 + r;
            #pragma unroll
            for (int nt = 0; nt < 2; ++nt) {
                const int col = wc * 32 + nt * 16 + l15;
                Ctx[qtile + trow * 64 + col] = bf16rne(ctx[mt][nt][r] * inv);
            }
        }
}

// ------------------------------------------------------------------
// oproj v3 (frozen from R7 — R11 fat-tile reverted: grid 384 halved
// occupancy-rounds and regressed). Single-pass Wo. Out = ctx @ WoH + bo.
// A from ctx tiles, BK=64, 32 KB LDS, XCD remap cpx=96.
// ------------------------------------------------------------------
__global__ __launch_bounds__(256, 4) void oproj(
    const unsigned short* __restrict__ Ctx,
    const unsigned short* __restrict__ WoH,
    const float* __restrict__ bo, float* __restrict__ out)
{
    __shared__ unsigned short As[8192];
    __shared__ unsigned short Bs[8192];

    const int tid  = threadIdx.x;
    const int lane = tid & 63;
    const int wv   = tid >> 6;
    const int wr   = wv >> 1, wc = wv & 1;
    const int q    = lane >> 4, l15 = lane & 15;

    const int s   = blockIdx.x + 6 * blockIdx.y;    // hw dispatch order
    const int lid = (s & 7) * 96 + (s >> 3);        // 768 wgs, cpx = 96
    const int n0  = (lid % 6) * 128;
    const int m0  = (lid / 6) * 128;

    const int srow   = tid >> 3;
    const int schunk = (tid & 7) ^ (srow & 7);

    char* ldsA = (char*)(&As[0]) + (wv << 10);
    char* ldsB = (char*)(&Bs[0]) + (wv << 10);

    f32x4 acc[4][4];
    #pragma unroll
    for (int i = 0; i < 4; ++i)
        #pragma unroll
        for (int j = 0; j < 4; ++j) acc[i][j] = 0;

    const int swz = (l15 & 7);

    for (int k0 = 0; k0 < H_DIM; k0 += 64) {
        const int h = k0 >> 6;   // BK=64 == head size: one head per k-iter
        #pragma unroll
        for (int i = 0; i < 4; ++i) {
            const int tok = m0 + i * 32 + srow;
            const long tile = ((long)(tok >> 9) * NHEADS + h) * 8 + ((tok >> 6) & 7);
            GLL16(Ctx + tile * 4096 + (long)(tok & 63) * 64 + schunk * 8, ldsA + i * 4096);
            GLL16(WoH + (long)(n0 + i * 32 + srow) * H_DIM + k0 + schunk * 8, ldsB + i * 4096);
        }
        __syncthreads();

        #pragma unroll
        for (int ks = 0; ks < 2; ++ks) {
            const int pc = ((ks * 4 + q) ^ swz) * 8;
            short8 ah[4], bh[4];
            #pragma unroll
            for (int t = 0; t < 4; ++t) {
                const int mr = wr * 64 + t * 16 + l15;
                ah[t] = *(const short8*)&As[mr * 64 + pc];
                const int nr = wc * 64 + t * 16 + l15;
                bh[t] = *(const short8*)&Bs[nr * 64 + pc];
            }
            #pragma unroll
            for (int mt = 0; mt < 4; ++mt)
                #pragma unroll
                for (int nt = 0; nt < 4; ++nt)
                    acc[mt][nt] = __builtin_amdgcn_mfma_f32_16x16x32_bf16(ah[mt], bh[nt], acc[mt][nt], 0, 0, 0);
        }
        __syncthreads();
    }

    #pragma unroll
    for (int nt = 0; nt < 4; ++nt) {
        const int col = n0 + wc * 64 + nt * 16 + l15;
        const float bcol = bo[col];
        #pragma unroll
        for (int mt = 0; mt < 4; ++mt) {
            const int rowB = m0 + wr * 64 + mt * 16 + q * 4;
            #pragma unroll
            for (int r = 0; r < 4; ++r)
                out[(long)(rowB + r) * H_DIM + col] = acc[mt][nt][r] + bcol;
        }
    }
}

extern "C" void kernel_launch(void* const* d_in, const int* in_sizes, int n_in,
                              void* d_out, int out_size, void* d_ws, size_t ws_size,
                              hipStream_t stream) {
    const float* X  = (const float*)d_in[0];
    const float* Wq = (const float*)d_in[1]; const float* bq = (const float*)d_in[2];
    const float* Wk = (const float*)d_in[3]; const float* bk = (const float*)d_in[4];
    const float* Wv = (const float*)d_in[5]; const float* bv = (const float*)d_in[6];
    const float* Wo = (const float*)d_in[7]; const float* bo = (const float*)d_in[8];

    unsigned short* wsu = (unsigned short*)d_ws;
    unsigned short* Qt  = wsu;                    // 12,582,912 (Q tiles bf16; ctx in place)
    unsigned short* Kp  = Qt + 12582912L;         // 12,582,912 (bf16 [bmh][p][d])
    unsigned short* Vp  = Kp + 12582912L;         // 12,582,912 (bf16 [bmh][d][p])
    unsigned short* Wt  = Vp + 12582912L;         // 4 planes x 589,824
    const long WP = (long)H_DIM * H_DIM;
    unsigned short* WqH = Wt;
    unsigned short* WkH = Wt + WP;
    unsigned short* WvH = Wt + 2 * WP;
    unsigned short* WoH = Wt + 3 * WP;

    // X~ lives in d_out (dead until oproj overwrites it)
    unsigned short* Xb = (unsigned short*)d_out;

    prep_all<<<6720, 256, 0, stream>>>(X, Xb, Wq, Wk, Wv, Wo,
                                       WqH, WkH, WvH, WoH);

    const float qscale = 0.125f * 1.4426950408889634f;   // softmax in base-2 domain
    qkv_gemm<<<dim3(1152), 256, 0, stream>>>(Xb, WqH, WkH, WvH,
                                             bq, bk, bv, qscale, Qt, Kp, Vp);

    attn2<<<dim3(4, 384), 256, 0, stream>>>(Qt, Kp, Vp, Qt);

    oproj<<<dim3(6, 128), 256, 0, stream>>>(Qt, WoH, bo, (float*)d_out);
}